// Round 3
// baseline (204.813 us; speedup 1.0000x reference)
//
#include <hip/hip_runtime.h>
#include <math.h>

constexpr int Bb = 2;
constexpr int Nn = 2048;
constexpr int Cc = 512;
constexpr int Hh = 8;
constexpr int Dd = 64;

typedef short short8 __attribute__((ext_vector_type(8)));
typedef float floatx4 __attribute__((ext_vector_type(4)));
typedef float floatx16 __attribute__((ext_vector_type(16)));

__device__ inline short8 bcs8(uint4 u) { return __builtin_bit_cast(short8, u); }

__device__ inline floatx4 mfma16(short8 a, short8 b, floatx4 c) {
    return __builtin_amdgcn_mfma_f32_16x16x32_bf16(a, b, c, 0, 0, 0);
}
__device__ inline floatx16 mfma32(short8 a, short8 b, floatx16 c) {
    return __builtin_amdgcn_mfma_f32_32x32x16_bf16(a, b, c, 0, 0, 0);
}

// async global->LDS, 16B per lane, dest = uniform base + lane*16
typedef __attribute__((address_space(1))) void gvoid;
typedef __attribute__((address_space(3))) void svoid;
__device__ inline void glds16(const void* g, void* l) {
    __builtin_amdgcn_global_load_lds((const gvoid*)g, (svoid*)l, 16, 0, 0);
}

// pack bf16(a)|bf16(b)<<16, truncation (hi/lo splits: lo compensates hi)
__device__ inline unsigned pk_trunc(float a, float b) {
    return __builtin_amdgcn_perm(__float_as_uint(b), __float_as_uint(a), 0x07060302u);
}
// RNE pack
__device__ inline unsigned pk_rne(float a, float b) {
    unsigned ua = __float_as_uint(a); ua += 0x7fffu + ((ua >> 16) & 1u);
    unsigned ub = __float_as_uint(b); ub += 0x7fffu + ((ub >> 16) & 1u);
    return __builtin_amdgcn_perm(ub, ua, 0x07060302u);
}
__device__ inline unsigned short rne1(float a) {
    unsigned u = __float_as_uint(a); u += 0x7fffu + ((u >> 16) & 1u);
    return (unsigned short)(u >> 16);
}
__device__ inline float tr16(float a) {
    return __uint_as_float(__float_as_uint(a) & 0xffff0000u);
}
__device__ inline void split8(float4 A, float4 B, uint4& hi, uint4& lo) {
    hi = make_uint4(pk_trunc(A.x, A.y), pk_trunc(A.z, A.w),
                    pk_trunc(B.x, B.y), pk_trunc(B.z, B.w));
    lo = make_uint4(pk_trunc(A.x - tr16(A.x), A.y - tr16(A.y)),
                    pk_trunc(A.z - tr16(A.z), A.w - tr16(A.w)),
                    pk_trunc(B.x - tr16(B.x), B.y - tr16(B.y)),
                    pk_trunc(B.z - tr16(B.z), B.w - tr16(B.w)));
}

// ---------------------------------------------------------------------------
// Weight prep: transpose + hi/lo split (unchanged from round 2).
// ---------------------------------------------------------------------------
__global__ __launch_bounds__(256) void wprep(const float* __restrict__ qkv_w,
                                             const float* __restrict__ proj_w,
                                             unsigned short* __restrict__ wqh,
                                             unsigned short* __restrict__ wql,
                                             unsigned short* __restrict__ wph,
                                             unsigned short* __restrict__ wpl)
{
    __shared__ float Tl[64][68];
    int bid = blockIdx.x;
    const float* src; unsigned short *dh, *dlo; int W, f0, k0;
    if (bid < 192) { int kt = bid / 24, ft = bid % 24; W = 1536; src = qkv_w; dh = wqh; dlo = wql; f0 = ft * 64; k0 = kt * 64; }
    else { int b2 = bid - 192; int kt = b2 / 8, ft = b2 % 8; W = 512; src = proj_w; dh = wph; dlo = wpl; f0 = ft * 64; k0 = kt * 64; }
    int t = threadIdx.x;
    {
        int kl = t >> 2, fc = (t & 3) * 16;
        const float* p = src + (size_t)(k0 + kl) * W + f0 + fc;
        #pragma unroll
        for (int i = 0; i < 4; ++i) {
            float4 v = *(const float4*)(p + i * 4);
            Tl[kl][fc + i * 4 + 0] = v.x; Tl[kl][fc + i * 4 + 1] = v.y;
            Tl[kl][fc + i * 4 + 2] = v.z; Tl[kl][fc + i * 4 + 3] = v.w;
        }
    }
    __syncthreads();
    {
        int fl = t >> 2, kc = (t & 3) * 16;
        float v[16];
        #pragma unroll
        for (int i = 0; i < 16; ++i) v[i] = Tl[kc + i][fl];
        unsigned hi[8], lo[8];
        #pragma unroll
        for (int i = 0; i < 8; ++i) {
            float a = v[2 * i], b = v[2 * i + 1];
            hi[i] = pk_trunc(a, b);
            lo[i] = pk_trunc(a - tr16(a), b - tr16(b));
        }
        unsigned short* oh = dh + (size_t)(f0 + fl) * 512 + k0 + kc;
        unsigned short* ol = dlo + (size_t)(f0 + fl) * 512 + k0 + kc;
        *(uint4*)oh = make_uint4(hi[0], hi[1], hi[2], hi[3]);
        *(uint4*)(oh + 8) = make_uint4(hi[4], hi[5], hi[6], hi[7]);
        *(uint4*)ol = make_uint4(lo[0], lo[1], lo[2], lo[3]);
        *(uint4*)(ol + 8) = make_uint4(lo[4], lo[5], lo[6], lo[7]);
    }
}

// ---------------------------------------------------------------------------
// x prep: fp32 (4096x512) -> xh/xl bf16 row-major. grid 512 x 256thr.
// ---------------------------------------------------------------------------
__global__ __launch_bounds__(256) void xprep(const float* __restrict__ x,
                                             unsigned short* __restrict__ xh,
                                             unsigned short* __restrict__ xl)
{
    size_t base = ((size_t)blockIdx.x * 256 + threadIdx.x) * 16;
    float4 a = *(const float4*)(x + base);
    float4 b = *(const float4*)(x + base + 4);
    float4 c = *(const float4*)(x + base + 8);
    float4 d = *(const float4*)(x + base + 12);
    uint4 h0, L0, h1, L1;
    split8(a, b, h0, L0); split8(c, d, h1, L1);
    *(uint4*)(xh + base) = h0; *(uint4*)(xh + base + 8) = h1;
    *(uint4*)(xl + base) = L0; *(uint4*)(xl + base + 8) = L1;
}

// ---------------------------------------------------------------------------
// GEMM1: qkvb = x(split) @ qkv_w(split,T), q pre-scaled. Pure glds16 staging.
// BM=128 BN=64 BK=32, 256 thr = 4 waves of 64x32. grid (24, 32) = 768 blocks.
// ---------------------------------------------------------------------------
__global__ __launch_bounds__(256, 3) void gemm_qkv(const unsigned short* __restrict__ xh,
                                                   const unsigned short* __restrict__ xl,
                                                   const unsigned short* __restrict__ wh,
                                                   const unsigned short* __restrict__ wl,
                                                   unsigned short* __restrict__ qkvb)
{
    __shared__ __align__(16) char smem[24576];
    char* Ah = smem; char* Al = smem + 8192; char* Bh = smem + 16384; char* Bl = smem + 20480;
    const int tid = threadIdx.x, lane = tid & 63, w = tid >> 6;
    const int l15 = lane & 15, l4 = lane >> 4;
    const int row0 = blockIdx.y * 128, col0 = blockIdx.x * 64;
    const int wm = w >> 1, wn = w & 1;

    floatx4 acc[4][2];
    #pragma unroll
    for (int i = 0; i < 4; ++i)
        #pragma unroll
        for (int j = 0; j < 2; ++j)
            #pragma unroll
            for (int r = 0; r < 4; ++r) acc[i][j][r] = 0.f;

    for (int k0 = 0; k0 < 512; k0 += 32) {
        #pragma unroll
        for (int i = 0; i < 4; ++i) {            // A: 16 segs (8 mt x hi/lo)
            int sid = w * 4 + i; int mt = sid >> 1, comp = sid & 1;
            const unsigned short* src = (comp ? xl : xh) + (size_t)(row0 + mt * 16 + l15) * 512 + k0 + l4 * 8;
            glds16(src, (comp ? Al : Ah) + mt * 1024);
        }
        #pragma unroll
        for (int i = 0; i < 2; ++i) {            // B: 8 segs (4 nt x hi/lo)
            int sid = w * 2 + i; int nt = sid >> 1, comp = sid & 1;
            const unsigned short* src = (comp ? wl : wh) + (size_t)(col0 + nt * 16 + l15) * 512 + k0 + l4 * 8;
            glds16(src, (comp ? Bl : Bh) + nt * 1024);
        }
        __syncthreads();
        short8 af[4][2], bf[2][2];
        #pragma unroll
        for (int mt = 0; mt < 4; ++mt) {
            int off = ((wm * 4 + mt) << 10) + (lane << 4);
            af[mt][0] = bcs8(*(const uint4*)(Ah + off));
            af[mt][1] = bcs8(*(const uint4*)(Al + off));
        }
        #pragma unroll
        for (int nt = 0; nt < 2; ++nt) {
            int off = ((wn * 2 + nt) << 10) + (lane << 4);
            bf[nt][0] = bcs8(*(const uint4*)(Bh + off));
            bf[nt][1] = bcs8(*(const uint4*)(Bl + off));
        }
        #pragma unroll
        for (int mt = 0; mt < 4; ++mt)
            #pragma unroll
            for (int nt = 0; nt < 2; ++nt) {
                acc[mt][nt] = mfma16(af[mt][0], bf[nt][0], acc[mt][nt]);
                acc[mt][nt] = mfma16(af[mt][0], bf[nt][1], acc[mt][nt]);
                acc[mt][nt] = mfma16(af[mt][1], bf[nt][0], acc[mt][nt]);
            }
        __syncthreads();
    }
    #pragma unroll
    for (int mt = 0; mt < 4; ++mt)
        #pragma unroll
        for (int nt = 0; nt < 2; ++nt) {
            int c = col0 + (wn * 2 + nt) * 16 + l15;
            float s = (c < 512) ? 0.125f : 1.0f;
            #pragma unroll
            for (int r = 0; r < 4; ++r) {
                int tok = row0 + (wm * 4 + mt) * 16 + l4 * 4 + r;
                qkvb[(size_t)tok * 1536 + c] = rne1(acc[mt][nt][r] * s);
            }
        }
}

// ---------------------------------------------------------------------------
// V transpose: qkvb v-section [tok][d] -> vt[bh][d][n]. (unchanged)
// ---------------------------------------------------------------------------
__global__ __launch_bounds__(256) void vtrans(const unsigned short* __restrict__ qkvb,
                                              unsigned short* __restrict__ vt)
{
    __shared__ unsigned short Tb[64][72];
    int bh = blockIdx.x >> 5, n0 = (blockIdx.x & 31) * 64;
    int b = bh >> 3, hh = bh & 7;
    int t = threadIdx.x;
    {
        int nl = t >> 2, dc = (t & 3) * 16;
        const unsigned short* src = qkvb + (size_t)(b * 2048 + n0 + nl) * 1536 + 1024 + hh * 64 + dc;
        unsigned short tmp[16];
        *(uint4*)tmp = *(const uint4*)src;
        *(uint4*)(tmp + 8) = *(const uint4*)(src + 8);
        #pragma unroll
        for (int i = 0; i < 16; ++i) Tb[dc + i][nl] = tmp[i];
    }
    __syncthreads();
    {
        int dl = t >> 2, nc = (t & 3) * 16;
        uint4 v0 = *(const uint4*)&Tb[dl][nc];
        uint4 v1 = *(const uint4*)&Tb[dl][nc + 8];
        unsigned short* dst = vt + (size_t)(bh * 64 + dl) * 2048 + n0 + nc;
        *(uint4*)dst = v0; *(uint4*)(dst + 8) = v1;
    }
}

// ---------------------------------------------------------------------------
// Attention: 32-query tiles, grid 1024 (bh x 64 qtiles, XCD-swizzled),
// 256 thr = 4 waves; wave kg owns 32 keys of each 128-key chunk.
// S^T = K.Q^T (mfma32); P via half-swap shuffle; O merged across waves in LDS.
// LDS 32 KB -> 4 blocks/CU.
// ---------------------------------------------------------------------------
__global__ __launch_bounds__(256, 4) void attn(const unsigned short* __restrict__ qkvb,
                                               const unsigned short* __restrict__ vt,
                                               unsigned short* __restrict__ Oh,
                                               unsigned short* __restrict__ Ol)
{
    __shared__ __align__(16) char smem[32768];
    char* Kst = smem;            // 16 KB: segs (mt 0..3, s 0..3)
    char* Vst = smem + 16384;    // 16 KB: segs (mtv 0..1, sv 0..7)

    int bid = blockIdx.x;
    int xcd = bid & 7; int rr = bid >> 3;
    int qt = rr & 63; int bhi = rr >> 6;
    int bh = (bhi << 3) | xcd;
    int b = bh >> 3, hh = bh & 7;
    int tid = threadIdx.x, lane = tid & 63, kg = tid >> 6;
    int l31 = lane & 31, h = lane >> 5;
    int tok0 = b * 2048 + qt * 32;

    // Q^T fragments (B-operand), once from global
    short8 qf[4];
    #pragma unroll
    for (int s = 0; s < 4; ++s) {
        const unsigned short* qs = qkvb + (size_t)(tok0 + l31) * 1536 + hh * 64 + s * 16 + h * 8;
        qf[s] = bcs8(*(const uint4*)qs);
    }

    floatx16 OT[2];
    #pragma unroll
    for (int i = 0; i < 2; ++i)
        #pragma unroll
        for (int r = 0; r < 16; ++r) OT[i][r] = 0.f;
    float lacc = 0.f;

    for (int ks0 = 0; ks0 < 2048; ks0 += 128) {
        #pragma unroll
        for (int i = 0; i < 4; ++i) {     // K: 16 segs of 1 KB
            int sid = kg * 4 + i; int mt = sid >> 2, s = sid & 3;
            const unsigned short* src = qkvb + (size_t)(b * 2048 + ks0 + mt * 32 + l31) * 1536 + 512 + hh * 64 + s * 16 + h * 8;
            glds16(src, Kst + ((mt << 2) + s) * 1024);
        }
        #pragma unroll
        for (int i = 0; i < 4; ++i) {     // V^T: 16 segs
            int sid = kg * 4 + i; int mtv = sid >> 3, sv = sid & 7;
            const unsigned short* src = vt + (size_t)(bh * 64 + mtv * 32 + l31) * 2048 + ks0 + sv * 16 + h * 8;
            glds16(src, Vst + ((mtv << 3) + sv) * 1024);
        }
        __syncthreads();

        short8 kf[4];
        #pragma unroll
        for (int s = 0; s < 4; ++s)
            kf[s] = bcs8(*(const uint4*)(Kst + ((kg << 2) + s) * 1024 + (lane << 4)));
        short8 vf[2][2];
        #pragma unroll
        for (int kc = 0; kc < 2; ++kc) {
            int sv = kg * 2 + kc;
            vf[kc][0] = bcs8(*(const uint4*)(Vst + sv * 1024 + (lane << 4)));
            vf[kc][1] = bcs8(*(const uint4*)(Vst + (8 + sv) * 1024 + (lane << 4)));
        }

        floatx16 st;
        #pragma unroll
        for (int r = 0; r < 16; ++r) st[r] = 0.f;
        #pragma unroll
        for (int s = 0; s < 4; ++s) st = mfma32(kf[s], qf[s], st);

        unsigned P2[8]; float ssum = 0.f;
        #pragma unroll
        for (int s2 = 0; s2 < 8; ++s2) {
            float e0 = __expf(st[2 * s2]), e1 = __expf(st[2 * s2 + 1]);
            ssum += e0 + e1;
            P2[s2] = pk_rne(e0, e1);
        }
        lacc += ssum;

        #pragma unroll
        for (int kc = 0; kc < 2; ++kc) {
            unsigned X0 = P2[4 * kc + 0], X1 = P2[4 * kc + 1];
            unsigned Y0 = P2[4 * kc + 2], Y1 = P2[4 * kc + 3];
            unsigned Xo0 = __shfl_xor(X0, 32, 64), Xo1 = __shfl_xor(X1, 32, 64);
            unsigned Yo0 = __shfl_xor(Y0, 32, 64), Yo1 = __shfl_xor(Y1, 32, 64);
            uint4 fu;
            fu.x = h ? Yo0 : X0;
            fu.y = h ? Yo1 : X1;
            fu.z = h ? Y0 : Xo0;
            fu.w = h ? Y1 : Xo1;
            short8 pf = bcs8(fu);
            OT[0] = mfma32(vf[kc][0], pf, OT[0]);
            OT[1] = mfma32(vf[kc][1], pf, OT[1]);
        }
        __syncthreads();
    }

    // ---- merge partial O/l across the 4 kg waves ----
    float* Mq = (float*)smem;                    // [d(64)][q(32)] = 8 KB
    float* Lq = (float*)(smem + 16384);          // [h(2)][q(32)]
    float* Tq = (float*)(smem + 16384 + 1024);   // [q(32)][68]

    if (kg == 3) {
        #pragma unroll
        for (int mtv = 0; mtv < 2; ++mtv)
            #pragma unroll
            for (int r = 0; r < 16; ++r) {
                int d = mtv * 32 + (r & 3) + 8 * (r >> 2) + 4 * h;
                Mq[d * 32 + l31] = OT[mtv][r];
            }
        Lq[h * 32 + l31] = lacc;
    }
    __syncthreads();
    if (kg == 2) {
        #pragma unroll
        for (int mtv = 0; mtv < 2; ++mtv)
            #pragma unroll
            for (int r = 0; r < 16; ++r) {
                int d = mtv * 32 + (r & 3) + 8 * (r >> 2) + 4 * h;
                Mq[d * 32 + l31] += OT[mtv][r];
            }
        Lq[h * 32 + l31] += lacc;
    }
    __syncthreads();
    if (kg == 1) {
        #pragma unroll
        for (int mtv = 0; mtv < 2; ++mtv)
            #pragma unroll
            for (int r = 0; r < 16; ++r) {
                int d = mtv * 32 + (r & 3) + 8 * (r >> 2) + 4 * h;
                Mq[d * 32 + l31] += OT[mtv][r];
            }
        Lq[h * 32 + l31] += lacc;
    }
    __syncthreads();
    if (kg == 0) {
        #pragma unroll
        for (int mtv = 0; mtv < 2; ++mtv)
            #pragma unroll
            for (int r = 0; r < 16; ++r) {
                int d = mtv * 32 + (r & 3) + 8 * (r >> 2) + 4 * h;
                OT[mtv][r] += Mq[d * 32 + l31];
            }
        Lq[h * 32 + l31] += lacc;
    }
    __syncthreads();
    if (kg == 0) {
        float inv = 1.f / (Lq[l31] + Lq[32 + l31]);
        #pragma unroll
        for (int mtv = 0; mtv < 2; ++mtv)
            #pragma unroll
            for (int r = 0; r < 16; ++r) {
                int d = mtv * 32 + (r & 3) + 8 * (r >> 2) + 4 * h;
                Tq[l31 * 68 + d] = OT[mtv][r] * inv;
            }
    }
    __syncthreads();
    // all 256 threads: coalesced split-bf16 store of O (flat B,H,N,D)
    {
        int q = tid >> 3, dc = (tid & 7) * 8;
        float vv[8];
        #pragma unroll
        for (int i = 0; i < 8; ++i) vv[i] = Tq[q * 68 + dc + i];
        unsigned hi[4], lo[4];
        #pragma unroll
        for (int i = 0; i < 4; ++i) {
            float a = vv[2 * i], bb = vv[2 * i + 1];
            hi[i] = pk_trunc(a, bb);
            lo[i] = pk_trunc(a - tr16(a), bb - tr16(bb));
        }
        size_t bo = ((size_t)(bh * 2048 + qt * 32 + q)) * 64 + dc;
        *(uint4*)(Oh + bo) = make_uint4(hi[0], hi[1], hi[2], hi[3]);
        *(uint4*)(Ol + bo) = make_uint4(lo[0], lo[1], lo[2], lo[3]);
    }
}

// ---------------------------------------------------------------------------
// GEMM2: out = O(split) @ proj_w(split,T) + bias. BM=64 BN=64 BK=32,
// 256 thr = 4 waves of 32x32. grid (8, 64) = 512 blocks.
// ---------------------------------------------------------------------------
__global__ __launch_bounds__(256, 2) void gemm_proj(const unsigned short* __restrict__ Ah_g,
                                                    const unsigned short* __restrict__ Al_g,
                                                    const unsigned short* __restrict__ wh,
                                                    const unsigned short* __restrict__ wl,
                                                    const float* __restrict__ bias,
                                                    float* __restrict__ out)
{
    __shared__ __align__(16) char smem[16384];
    char* Ah = smem; char* Al = smem + 4096; char* Bh = smem + 8192; char* Bl = smem + 12288;
    const int tid = threadIdx.x, lane = tid & 63, w = tid >> 6;
    const int l15 = lane & 15, l4 = lane >> 4;
    const int row0 = blockIdx.y * 64, col0 = blockIdx.x * 64;
    const int wm = w >> 1, wn = w & 1;

    floatx4 acc[2][2];
    #pragma unroll
    for (int i = 0; i < 2; ++i)
        #pragma unroll
        for (int j = 0; j < 2; ++j)
            #pragma unroll
            for (int r = 0; r < 4; ++r) acc[i][j][r] = 0.f;

    for (int k0 = 0; k0 < 512; k0 += 32) {
        #pragma unroll
        for (int i = 0; i < 4; ++i) {      // 16 segs: 8 A (mt x hi/lo) + 8 B
            int sid = w * 4 + i;
            if (sid < 8) {
                int mt = sid >> 1, comp = sid & 1;
                const unsigned short* src = (comp ? Al_g : Ah_g) + (size_t)(row0 + mt * 16 + l15) * 512 + k0 + l4 * 8;
                glds16(src, (comp ? Al : Ah) + mt * 1024);
            } else {
                int s2 = sid - 8; int nt = s2 >> 1, comp = s2 & 1;
                const unsigned short* src = (comp ? wl : wh) + (size_t)(col0 + nt * 16 + l15) * 512 + k0 + l4 * 8;
                glds16(src, (comp ? Bl : Bh) + nt * 1024);
            }
        }
        __syncthreads();
        short8 af[2][2], bf[2][2];
        #pragma unroll
        for (int mt = 0; mt < 2; ++mt) {
            int off = ((wm * 2 + mt) << 10) + (lane << 4);
            af[mt][0] = bcs8(*(const uint4*)(Ah + off));
            af[mt][1] = bcs8(*(const uint4*)(Al + off));
        }
        #pragma unroll
        for (int nt = 0; nt < 2; ++nt) {
            int off = ((wn * 2 + nt) << 10) + (lane << 4);
            bf[nt][0] = bcs8(*(const uint4*)(Bh + off));
            bf[nt][1] = bcs8(*(const uint4*)(Bl + off));
        }
        #pragma unroll
        for (int mt = 0; mt < 2; ++mt)
            #pragma unroll
            for (int nt = 0; nt < 2; ++nt) {
                acc[mt][nt] = mfma16(af[mt][0], bf[nt][0], acc[mt][nt]);
                acc[mt][nt] = mfma16(af[mt][0], bf[nt][1], acc[mt][nt]);
                acc[mt][nt] = mfma16(af[mt][1], bf[nt][0], acc[mt][nt]);
            }
        __syncthreads();
    }
    #pragma unroll
    for (int mt = 0; mt < 2; ++mt)
        #pragma unroll
        for (int nt = 0; nt < 2; ++nt) {
            int c = col0 + (wn * 2 + nt) * 16 + l15;
            float bv = bias[c];
            #pragma unroll
            for (int r = 0; r < 4; ++r) {
                int tok = row0 + (wm * 2 + mt) * 16 + l4 * 4 + r;
                out[(size_t)tok * 512 + c] = acc[mt][nt][r] + bv;
            }
        }
}

// ---------------------------------------------------------------------------
extern "C" void kernel_launch(void* const* d_in, const int* in_sizes, int n_in,
                              void* d_out, int out_size, void* d_ws, size_t ws_size,
                              hipStream_t stream)
{
    const float* x      = (const float*)d_in[0];
    const float* qkv_w  = (const float*)d_in[1];
    const float* proj_w = (const float*)d_in[2];
    const float* proj_b = (const float*)d_in[3];
    float* out = (float*)d_out;

    char* ws = (char*)d_ws;
    unsigned short* qkvb = (unsigned short*)ws;                      // 12 MiB
    unsigned short* vt   = (unsigned short*)(ws + 12582912);         //  4 MiB
    unsigned short* wqh  = (unsigned short*)(ws + 16777216);         // 1.5 MiB
    unsigned short* wql  = (unsigned short*)(ws + 18350080);         // 1.5 MiB
    unsigned short* wph  = (unsigned short*)(ws + 19922944);         // 0.5 MiB
    unsigned short* wpl  = (unsigned short*)(ws + 20447232);         // 0.5 MiB
    unsigned short* Oh   = (unsigned short*)(ws + 20971520);         //  4 MiB
    unsigned short* Ol   = (unsigned short*)(ws + 25165824);         //  4 MiB (end 28 MiB)
    // xh/xl overlay Oh/Ol: consumed by gemm_qkv before attn writes Oh/Ol.
    unsigned short* xh = Oh;
    unsigned short* xl = Ol;

    wprep<<<256, 256, 0, stream>>>(qkv_w, proj_w, wqh, wql, wph, wpl);
    xprep<<<512, 256, 0, stream>>>(x, xh, xl);
    gemm_qkv<<<dim3(24, 32), 256, 0, stream>>>(xh, xl, wqh, wql, qkvb);
    vtrans<<<512, 256, 0, stream>>>(qkvb, vt);
    attn<<<1024, 256, 0, stream>>>(qkvb, vt, Oh, Ol);
    gemm_proj<<<dim3(8, 64), 256, 0, stream>>>(Oh, Ol, wph, wpl, proj_b, out);
}

// Round 4
// 169.147 us; speedup vs baseline: 1.2109x; 1.2109x over previous
//
#include <hip/hip_runtime.h>
#include <math.h>

constexpr int Bb = 2;
constexpr int Nn = 2048;
constexpr int Cc = 512;
constexpr int Hh = 8;
constexpr int Dd = 64;

typedef short short8 __attribute__((ext_vector_type(8)));
typedef float floatx4 __attribute__((ext_vector_type(4)));
typedef float floatx16 __attribute__((ext_vector_type(16)));

__device__ inline short8 bcs8(uint4 u) { return __builtin_bit_cast(short8, u); }

__device__ inline floatx4 mfma16(short8 a, short8 b, floatx4 c) {
    return __builtin_amdgcn_mfma_f32_16x16x32_bf16(a, b, c, 0, 0, 0);
}
__device__ inline floatx16 mfma32(short8 a, short8 b, floatx16 c) {
    return __builtin_amdgcn_mfma_f32_32x32x16_bf16(a, b, c, 0, 0, 0);
}

// async global->LDS, 16B per lane, dest = uniform base + lane*16
typedef __attribute__((address_space(1))) void gvoid;
typedef __attribute__((address_space(3))) void svoid;
__device__ inline void glds16(const void* g, void* l) {
    __builtin_amdgcn_global_load_lds((const gvoid*)g, (svoid*)l, 16, 0, 0);
}

// pack bf16(a)|bf16(b)<<16, truncation (hi/lo splits: lo compensates hi)
__device__ inline unsigned pk_trunc(float a, float b) {
    return __builtin_amdgcn_perm(__float_as_uint(b), __float_as_uint(a), 0x07060302u);
}
// RNE pack
__device__ inline unsigned pk_rne(float a, float b) {
    unsigned ua = __float_as_uint(a); ua += 0x7fffu + ((ua >> 16) & 1u);
    unsigned ub = __float_as_uint(b); ub += 0x7fffu + ((ub >> 16) & 1u);
    return __builtin_amdgcn_perm(ub, ua, 0x07060302u);
}
__device__ inline unsigned short rne1(float a) {
    unsigned u = __float_as_uint(a); u += 0x7fffu + ((u >> 16) & 1u);
    return (unsigned short)(u >> 16);
}
__device__ inline float tr16(float a) {
    return __uint_as_float(__float_as_uint(a) & 0xffff0000u);
}
__device__ inline void split8(float4 A, float4 B, uint4& hi, uint4& lo) {
    hi = make_uint4(pk_trunc(A.x, A.y), pk_trunc(A.z, A.w),
                    pk_trunc(B.x, B.y), pk_trunc(B.z, B.w));
    lo = make_uint4(pk_trunc(A.x - tr16(A.x), A.y - tr16(A.y)),
                    pk_trunc(A.z - tr16(A.z), A.w - tr16(A.w)),
                    pk_trunc(B.x - tr16(B.x), B.y - tr16(B.y)),
                    pk_trunc(B.z - tr16(B.z), B.w - tr16(B.w)));
}

// ---------------------------------------------------------------------------
// Weight prep: transpose + hi/lo split (unchanged).
// ---------------------------------------------------------------------------
__global__ __launch_bounds__(256) void wprep(const float* __restrict__ qkv_w,
                                             const float* __restrict__ proj_w,
                                             unsigned short* __restrict__ wqh,
                                             unsigned short* __restrict__ wql,
                                             unsigned short* __restrict__ wph,
                                             unsigned short* __restrict__ wpl)
{
    __shared__ float Tl[64][68];
    int bid = blockIdx.x;
    const float* src; unsigned short *dh, *dlo; int W, f0, k0;
    if (bid < 192) { int kt = bid / 24, ft = bid % 24; W = 1536; src = qkv_w; dh = wqh; dlo = wql; f0 = ft * 64; k0 = kt * 64; }
    else { int b2 = bid - 192; int kt = b2 / 8, ft = b2 % 8; W = 512; src = proj_w; dh = wph; dlo = wpl; f0 = ft * 64; k0 = kt * 64; }
    int t = threadIdx.x;
    {
        int kl = t >> 2, fc = (t & 3) * 16;
        const float* p = src + (size_t)(k0 + kl) * W + f0 + fc;
        #pragma unroll
        for (int i = 0; i < 4; ++i) {
            float4 v = *(const float4*)(p + i * 4);
            Tl[kl][fc + i * 4 + 0] = v.x; Tl[kl][fc + i * 4 + 1] = v.y;
            Tl[kl][fc + i * 4 + 2] = v.z; Tl[kl][fc + i * 4 + 3] = v.w;
        }
    }
    __syncthreads();
    {
        int fl = t >> 2, kc = (t & 3) * 16;
        float v[16];
        #pragma unroll
        for (int i = 0; i < 16; ++i) v[i] = Tl[kc + i][fl];
        unsigned hi[8], lo[8];
        #pragma unroll
        for (int i = 0; i < 8; ++i) {
            float a = v[2 * i], b = v[2 * i + 1];
            hi[i] = pk_trunc(a, b);
            lo[i] = pk_trunc(a - tr16(a), b - tr16(b));
        }
        unsigned short* oh = dh + (size_t)(f0 + fl) * 512 + k0 + kc;
        unsigned short* ol = dlo + (size_t)(f0 + fl) * 512 + k0 + kc;
        *(uint4*)oh = make_uint4(hi[0], hi[1], hi[2], hi[3]);
        *(uint4*)(oh + 8) = make_uint4(hi[4], hi[5], hi[6], hi[7]);
        *(uint4*)ol = make_uint4(lo[0], lo[1], lo[2], lo[3]);
        *(uint4*)(ol + 8) = make_uint4(lo[4], lo[5], lo[6], lo[7]);
    }
}

// ---------------------------------------------------------------------------
// x prep: fp32 (4096x512) -> xh/xl bf16 row-major. grid 512 x 256thr.
// ---------------------------------------------------------------------------
__global__ __launch_bounds__(256) void xprep(const float* __restrict__ x,
                                             unsigned short* __restrict__ xh,
                                             unsigned short* __restrict__ xl)
{
    size_t base = ((size_t)blockIdx.x * 256 + threadIdx.x) * 16;
    float4 a = *(const float4*)(x + base);
    float4 b = *(const float4*)(x + base + 4);
    float4 c = *(const float4*)(x + base + 8);
    float4 d = *(const float4*)(x + base + 12);
    uint4 h0, L0, h1, L1;
    split8(a, b, h0, L0); split8(c, d, h1, L1);
    *(uint4*)(xh + base) = h0; *(uint4*)(xh + base + 8) = h1;
    *(uint4*)(xl + base) = L0; *(uint4*)(xl + base + 8) = L1;
}

// ---------------------------------------------------------------------------
// GEMM1: x(split) @ qkv_w(split,T) -> DENSE qd/kd/vd[bh][n][64] bf16
// (q pre-scaled by 1/8). BM=128 BN=64 BK=32, 256 thr. grid (24,32).
// ---------------------------------------------------------------------------
__global__ __launch_bounds__(256, 3) void gemm_qkv(const unsigned short* __restrict__ xh,
                                                   const unsigned short* __restrict__ xl,
                                                   const unsigned short* __restrict__ wh,
                                                   const unsigned short* __restrict__ wl,
                                                   unsigned short* __restrict__ qd,
                                                   unsigned short* __restrict__ kd,
                                                   unsigned short* __restrict__ vd)
{
    __shared__ __align__(16) char smem[24576];
    char* Ah = smem; char* Al = smem + 8192; char* Bh = smem + 16384; char* Bl = smem + 20480;
    const int tid = threadIdx.x, lane = tid & 63, w = tid >> 6;
    const int l15 = lane & 15, l4 = lane >> 4;
    const int row0 = blockIdx.y * 128, col0 = blockIdx.x * 64;
    const int wm = w >> 1, wn = w & 1;

    floatx4 acc[4][2];
    #pragma unroll
    for (int i = 0; i < 4; ++i)
        #pragma unroll
        for (int j = 0; j < 2; ++j)
            #pragma unroll
            for (int r = 0; r < 4; ++r) acc[i][j][r] = 0.f;

    for (int k0 = 0; k0 < 512; k0 += 32) {
        #pragma unroll
        for (int i = 0; i < 4; ++i) {            // A: 16 segs (8 mt x hi/lo)
            int sid = w * 4 + i; int mt = sid >> 1, comp = sid & 1;
            const unsigned short* src = (comp ? xl : xh) + (size_t)(row0 + mt * 16 + l15) * 512 + k0 + l4 * 8;
            glds16(src, (comp ? Al : Ah) + mt * 1024);
        }
        #pragma unroll
        for (int i = 0; i < 2; ++i) {            // B: 8 segs (4 nt x hi/lo)
            int sid = w * 2 + i; int nt = sid >> 1, comp = sid & 1;
            const unsigned short* src = (comp ? wl : wh) + (size_t)(col0 + nt * 16 + l15) * 512 + k0 + l4 * 8;
            glds16(src, (comp ? Bl : Bh) + nt * 1024);
        }
        __syncthreads();
        short8 af[4][2], bf[2][2];
        #pragma unroll
        for (int mt = 0; mt < 4; ++mt) {
            int off = ((wm * 4 + mt) << 10) + (lane << 4);
            af[mt][0] = bcs8(*(const uint4*)(Ah + off));
            af[mt][1] = bcs8(*(const uint4*)(Al + off));
        }
        #pragma unroll
        for (int nt = 0; nt < 2; ++nt) {
            int off = ((wn * 2 + nt) << 10) + (lane << 4);
            bf[nt][0] = bcs8(*(const uint4*)(Bh + off));
            bf[nt][1] = bcs8(*(const uint4*)(Bl + off));
        }
        #pragma unroll
        for (int mt = 0; mt < 4; ++mt)
            #pragma unroll
            for (int nt = 0; nt < 2; ++nt) {
                acc[mt][nt] = mfma16(af[mt][0], bf[nt][0], acc[mt][nt]);
                acc[mt][nt] = mfma16(af[mt][0], bf[nt][1], acc[mt][nt]);
                acc[mt][nt] = mfma16(af[mt][1], bf[nt][0], acc[mt][nt]);
            }
        __syncthreads();
    }
    // epilogue: route to dense q/k/v per-head layouts
    #pragma unroll
    for (int mt = 0; mt < 4; ++mt)
        #pragma unroll
        for (int nt = 0; nt < 2; ++nt) {
            int c = col0 + (wn * 2 + nt) * 16 + l15;     // 0..1535
            int which = c >> 9;                          // 0=q,1=k,2=v (block-uniform)
            int head = (c >> 6) & 7, d = c & 63;
            unsigned short* dst = (which == 0) ? qd : ((which == 1) ? kd : vd);
            float s = (which == 0) ? 0.125f : 1.0f;
            #pragma unroll
            for (int r = 0; r < 4; ++r) {
                int tok = row0 + (wm * 4 + mt) * 16 + l4 * 4 + r;
                int b = tok >> 11, n = tok & 2047;
                dst[(size_t)((b * 8 + head) * 2048 + n) * 64 + d] = rne1(acc[mt][nt][r] * s);
            }
        }
}

// ---------------------------------------------------------------------------
// V transpose: vd[bh][n][64] -> vt[bh][d][2048]. grid 512 x 256thr.
// ---------------------------------------------------------------------------
__global__ __launch_bounds__(256) void vtrans(const unsigned short* __restrict__ vd,
                                              unsigned short* __restrict__ vt)
{
    __shared__ unsigned short Tb[64][72];
    int bh = blockIdx.x >> 5, n0 = (blockIdx.x & 31) * 64;
    int t = threadIdx.x;
    {
        int nl = t >> 2, dc = (t & 3) * 16;
        const unsigned short* src = vd + (size_t)(bh * 2048 + n0 + nl) * 64 + dc;
        unsigned short tmp[16];
        *(uint4*)tmp = *(const uint4*)src;
        *(uint4*)(tmp + 8) = *(const uint4*)(src + 8);
        #pragma unroll
        for (int i = 0; i < 16; ++i) Tb[dc + i][nl] = tmp[i];
    }
    __syncthreads();
    {
        int dl = t >> 2, nc = (t & 3) * 16;
        uint4 v0 = *(const uint4*)&Tb[dl][nc];
        uint4 v1 = *(const uint4*)&Tb[dl][nc + 8];
        unsigned short* dst = vt + (size_t)(bh * 64 + dl) * 2048 + n0 + nc;
        *(uint4*)dst = v0; *(uint4*)(dst + 8) = v1;
    }
}

// ---------------------------------------------------------------------------
// Attention: 64-query blocks, 512 thr = 8 waves (qg 2 x kg 4).
// Grid 512 = 16 bh x 32 qtiles (XCD-swizzled). Chunk = 128 keys, LDS 36 KB.
// S^T = K.Q^T (mfma32); P via half-swap shuffle; per-qg merge across kg in LDS.
// Dense qd/kd/vt sources -> coalesced glds16 staging.
// ---------------------------------------------------------------------------
__global__ __launch_bounds__(512, 4) void attn(const unsigned short* __restrict__ qd,
                                               const unsigned short* __restrict__ kd,
                                               const unsigned short* __restrict__ vt,
                                               unsigned short* __restrict__ Oh,
                                               unsigned short* __restrict__ Ol)
{
    __shared__ __align__(16) char smem[36864];
    char* Kst = smem;            // 16 KB: segs (mt 0..3, s 0..3)
    char* Vst = smem + 16384;    // 16 KB: segs (mtv 0..1, sv 0..7)

    int bid = blockIdx.x;
    int xcd = bid & 7; int rr = bid >> 3;
    int qt = rr & 31; int bhi = rr >> 5;
    int bh = (bhi << 3) | xcd;
    int tid = threadIdx.x, lane = tid & 63, w = tid >> 6;
    int qg = w >> 2, kg = w & 3;
    int l31 = lane & 31, h = lane >> 5;

    // Q^T fragments (B-operand), once from dense qd (pre-scaled)
    short8 qf[4];
    #pragma unroll
    for (int s = 0; s < 4; ++s) {
        const unsigned short* qs = qd + (size_t)(bh * 2048 + qt * 64 + qg * 32 + l31) * 64 + s * 16 + h * 8;
        qf[s] = bcs8(*(const uint4*)qs);
    }

    floatx16 OT[2];
    #pragma unroll
    for (int i = 0; i < 2; ++i)
        #pragma unroll
        for (int r = 0; r < 16; ++r) OT[i][r] = 0.f;
    float lacc = 0.f;

    for (int ks0 = 0; ks0 < 2048; ks0 += 128) {
        #pragma unroll
        for (int i = 0; i < 2; ++i) {     // K: 16 segs of 1 KB
            int sid = w * 2 + i; int mt = sid >> 2, s = sid & 3;
            const unsigned short* src = kd + (size_t)(bh * 2048 + ks0 + mt * 32 + l31) * 64 + s * 16 + h * 8;
            glds16(src, Kst + sid * 1024);
        }
        #pragma unroll
        for (int i = 0; i < 2; ++i) {     // V^T: 16 segs
            int sid = w * 2 + i; int mtv = sid >> 3, sv = sid & 7;
            const unsigned short* src = vt + (size_t)(bh * 64 + mtv * 32 + l31) * 2048 + ks0 + sv * 16 + h * 8;
            glds16(src, Vst + sid * 1024);
        }
        __syncthreads();

        short8 kf[4];
        #pragma unroll
        for (int s = 0; s < 4; ++s)
            kf[s] = bcs8(*(const uint4*)(Kst + ((kg << 2) + s) * 1024 + (lane << 4)));
        short8 vf[2][2];
        #pragma unroll
        for (int kc = 0; kc < 2; ++kc) {
            int sv = kg * 2 + kc;
            vf[kc][0] = bcs8(*(const uint4*)(Vst + sv * 1024 + (lane << 4)));
            vf[kc][1] = bcs8(*(const uint4*)(Vst + (8 + sv) * 1024 + (lane << 4)));
        }

        floatx16 st;
        #pragma unroll
        for (int r = 0; r < 16; ++r) st[r] = 0.f;
        #pragma unroll
        for (int s = 0; s < 4; ++s) st = mfma32(kf[s], qf[s], st);

        unsigned P2[8]; float ssum = 0.f;
        #pragma unroll
        for (int s2 = 0; s2 < 8; ++s2) {
            float e0 = __expf(st[2 * s2]), e1 = __expf(st[2 * s2 + 1]);
            ssum += e0 + e1;
            P2[s2] = pk_rne(e0, e1);
        }
        lacc += ssum;

        #pragma unroll
        for (int kc = 0; kc < 2; ++kc) {
            unsigned X0 = P2[4 * kc + 0], X1 = P2[4 * kc + 1];
            unsigned Y0 = P2[4 * kc + 2], Y1 = P2[4 * kc + 3];
            unsigned Xo0 = __shfl_xor(X0, 32, 64), Xo1 = __shfl_xor(X1, 32, 64);
            unsigned Yo0 = __shfl_xor(Y0, 32, 64), Yo1 = __shfl_xor(Y1, 32, 64);
            uint4 fu;
            fu.x = h ? Yo0 : X0;
            fu.y = h ? Yo1 : X1;
            fu.z = h ? Y0 : Xo0;
            fu.w = h ? Y1 : Xo1;
            short8 pf = bcs8(fu);
            OT[0] = mfma32(vf[kc][0], pf, OT[0]);
            OT[1] = mfma32(vf[kc][1], pf, OT[1]);
        }
        __syncthreads();
    }

    // ---- merge partial O/l across the 4 kg waves, per qg ----
    float* Mq = (float*)smem + qg * 2048;                 // [d(64)][q(32)] 8 KB
    float* Lq = (float*)(smem + 16384) + qg * 64;         // [h(2)][q(32)]
    float* Tq = (float*)(smem + 16384 + 1024) + qg * 2176; // [q(32)][68]

    if (kg == 3) {
        #pragma unroll
        for (int mtv = 0; mtv < 2; ++mtv)
            #pragma unroll
            for (int r = 0; r < 16; ++r) {
                int d = mtv * 32 + (r & 3) + 8 * (r >> 2) + 4 * h;
                Mq[d * 32 + l31] = OT[mtv][r];
            }
        Lq[h * 32 + l31] = lacc;
    }
    __syncthreads();
    if (kg == 2) {
        #pragma unroll
        for (int mtv = 0; mtv < 2; ++mtv)
            #pragma unroll
            for (int r = 0; r < 16; ++r) {
                int d = mtv * 32 + (r & 3) + 8 * (r >> 2) + 4 * h;
                Mq[d * 32 + l31] += OT[mtv][r];
            }
        Lq[h * 32 + l31] += lacc;
    }
    __syncthreads();
    if (kg == 1) {
        #pragma unroll
        for (int mtv = 0; mtv < 2; ++mtv)
            #pragma unroll
            for (int r = 0; r < 16; ++r) {
                int d = mtv * 32 + (r & 3) + 8 * (r >> 2) + 4 * h;
                Mq[d * 32 + l31] += OT[mtv][r];
            }
        Lq[h * 32 + l31] += lacc;
    }
    __syncthreads();
    if (kg == 0) {
        #pragma unroll
        for (int mtv = 0; mtv < 2; ++mtv)
            #pragma unroll
            for (int r = 0; r < 16; ++r) {
                int d = mtv * 32 + (r & 3) + 8 * (r >> 2) + 4 * h;
                OT[mtv][r] += Mq[d * 32 + l31];
            }
        Lq[h * 32 + l31] += lacc;
    }
    __syncthreads();
    if (kg == 0) {
        float inv = 1.f / (Lq[l31] + Lq[32 + l31]);
        #pragma unroll
        for (int mtv = 0; mtv < 2; ++mtv)
            #pragma unroll
            for (int r = 0; r < 16; ++r) {
                int d = mtv * 32 + (r & 3) + 8 * (r >> 2) + 4 * h;
                Tq[l31 * 68 + d] = OT[mtv][r] * inv;
            }
    }
    __syncthreads();
    // all 512 threads: coalesced split-bf16 store of O (flat B,H,N,D)
    {
        int q = tid >> 3, dc = (tid & 7) * 8;             // q 0..63
        const float* T = (const float*)(smem + 16384 + 1024) + (q >> 5) * 2176;
        int ql = q & 31;
        float vv[8];
        #pragma unroll
        for (int i = 0; i < 8; ++i) vv[i] = T[ql * 68 + dc + i];
        unsigned hi[4], lo[4];
        #pragma unroll
        for (int i = 0; i < 4; ++i) {
            float a = vv[2 * i], bb = vv[2 * i + 1];
            hi[i] = pk_trunc(a, bb);
            lo[i] = pk_trunc(a - tr16(a), bb - tr16(bb));
        }
        size_t bo = ((size_t)(bh * 2048 + qt * 64 + q)) * 64 + dc;
        *(uint4*)(Oh + bo) = make_uint4(hi[0], hi[1], hi[2], hi[3]);
        *(uint4*)(Ol + bo) = make_uint4(lo[0], lo[1], lo[2], lo[3]);
    }
}

// ---------------------------------------------------------------------------
// GEMM2: out = O(split) @ proj_w(split,T) + bias. BM=64 BN=64 BK=32,
// 256 thr = 4 waves of 32x32. grid (8, 64) = 512 blocks.
// ---------------------------------------------------------------------------
__global__ __launch_bounds__(256, 2) void gemm_proj(const unsigned short* __restrict__ Ah_g,
                                                    const unsigned short* __restrict__ Al_g,
                                                    const unsigned short* __restrict__ wh,
                                                    const unsigned short* __restrict__ wl,
                                                    const float* __restrict__ bias,
                                                    float* __restrict__ out)
{
    __shared__ __align__(16) char smem[16384];
    char* Ah = smem; char* Al = smem + 4096; char* Bh = smem + 8192; char* Bl = smem + 12288;
    const int tid = threadIdx.x, lane = tid & 63, w = tid >> 6;
    const int l15 = lane & 15, l4 = lane >> 4;
    const int row0 = blockIdx.y * 64, col0 = blockIdx.x * 64;
    const int wm = w >> 1, wn = w & 1;

    floatx4 acc[2][2];
    #pragma unroll
    for (int i = 0; i < 2; ++i)
        #pragma unroll
        for (int j = 0; j < 2; ++j)
            #pragma unroll
            for (int r = 0; r < 4; ++r) acc[i][j][r] = 0.f;

    for (int k0 = 0; k0 < 512; k0 += 32) {
        #pragma unroll
        for (int i = 0; i < 4; ++i) {      // 16 segs: 8 A (mt x hi/lo) + 8 B
            int sid = w * 4 + i;
            if (sid < 8) {
                int mt = sid >> 1, comp = sid & 1;
                const unsigned short* src = (comp ? Al_g : Ah_g) + (size_t)(row0 + mt * 16 + l15) * 512 + k0 + l4 * 8;
                glds16(src, (comp ? Al : Ah) + mt * 1024);
            } else {
                int s2 = sid - 8; int nt = s2 >> 1, comp = s2 & 1;
                const unsigned short* src = (comp ? wl : wh) + (size_t)(col0 + nt * 16 + l15) * 512 + k0 + l4 * 8;
                glds16(src, (comp ? Bl : Bh) + nt * 1024);
            }
        }
        __syncthreads();
        short8 af[2][2], bf[2][2];
        #pragma unroll
        for (int mt = 0; mt < 2; ++mt) {
            int off = ((wm * 2 + mt) << 10) + (lane << 4);
            af[mt][0] = bcs8(*(const uint4*)(Ah + off));
            af[mt][1] = bcs8(*(const uint4*)(Al + off));
        }
        #pragma unroll
        for (int nt = 0; nt < 2; ++nt) {
            int off = ((wn * 2 + nt) << 10) + (lane << 4);
            bf[nt][0] = bcs8(*(const uint4*)(Bh + off));
            bf[nt][1] = bcs8(*(const uint4*)(Bl + off));
        }
        #pragma unroll
        for (int mt = 0; mt < 2; ++mt)
            #pragma unroll
            for (int nt = 0; nt < 2; ++nt) {
                acc[mt][nt] = mfma16(af[mt][0], bf[nt][0], acc[mt][nt]);
                acc[mt][nt] = mfma16(af[mt][0], bf[nt][1], acc[mt][nt]);
                acc[mt][nt] = mfma16(af[mt][1], bf[nt][0], acc[mt][nt]);
            }
        __syncthreads();
    }
    #pragma unroll
    for (int mt = 0; mt < 2; ++mt)
        #pragma unroll
        for (int nt = 0; nt < 2; ++nt) {
            int c = col0 + (wn * 2 + nt) * 16 + l15;
            float bv = bias[c];
            #pragma unroll
            for (int r = 0; r < 4; ++r) {
                int tok = row0 + (wm * 2 + mt) * 16 + l4 * 4 + r;
                out[(size_t)tok * 512 + c] = acc[mt][nt][r] + bv;
            }
        }
}

// ---------------------------------------------------------------------------
extern "C" void kernel_launch(void* const* d_in, const int* in_sizes, int n_in,
                              void* d_out, int out_size, void* d_ws, size_t ws_size,
                              hipStream_t stream)
{
    const float* x      = (const float*)d_in[0];
    const float* qkv_w  = (const float*)d_in[1];
    const float* proj_w = (const float*)d_in[2];
    const float* proj_b = (const float*)d_in[3];
    float* out = (float*)d_out;

    char* ws = (char*)d_ws;
    unsigned short* qd   = (unsigned short*)ws;                      //  4 MiB
    unsigned short* kd   = (unsigned short*)(ws + 4194304);          //  4 MiB
    unsigned short* vd   = (unsigned short*)(ws + 8388608);          //  4 MiB
    unsigned short* vt   = (unsigned short*)(ws + 12582912);         //  4 MiB
    unsigned short* wqh  = (unsigned short*)(ws + 16777216);         // 1.5 MiB
    unsigned short* wql  = (unsigned short*)(ws + 18350080);         // 1.5 MiB
    unsigned short* wph  = (unsigned short*)(ws + 19922944);         // 0.5 MiB
    unsigned short* wpl  = (unsigned short*)(ws + 20447232);         // 0.5 MiB
    unsigned short* Oh   = (unsigned short*)(ws + 20971520);         //  4 MiB
    unsigned short* Ol   = (unsigned short*)(ws + 25165824);         //  4 MiB (end 28 MiB)
    // xh/xl overlay Oh/Ol: consumed by gemm_qkv before attn writes Oh/Ol.
    unsigned short* xh = Oh;
    unsigned short* xl = Ol;

    wprep<<<256, 256, 0, stream>>>(qkv_w, proj_w, wqh, wql, wph, wpl);
    xprep<<<512, 256, 0, stream>>>(x, xh, xl);
    gemm_qkv<<<dim3(24, 32), 256, 0, stream>>>(xh, xl, wqh, wql, qd, kd, vd);
    vtrans<<<512, 256, 0, stream>>>(vd, vt);
    attn<<<512, 512, 0, stream>>>(qd, kd, vt, Oh, Ol);
    gemm_proj<<<dim3(8, 64), 256, 0, stream>>>(Oh, Ol, wph, wpl, proj_b, out);
}